// Round 1
// baseline (18.554 us; speedup 1.0000x reference)
//
#include <hip/hip_runtime.h>

// One 64-lane wave per batch element.
//  - dot(user_factors[u], item_factors[it]) : one element per lane + shfl_xor tree
//  - ratings row (L=256 floats = 1KB)       : one float4 per lane, fully coalesced
//  - mass: per-lane partial over 4 entries, shfl_xor tree reduce
__global__ __launch_bounds__(256) void hist_mf_kernel(
    const int*   __restrict__ users,
    const int*   __restrict__ items,
    const int*   __restrict__ item_pos,
    const float* __restrict__ ratings,
    const float* __restrict__ user_factors,
    const float* __restrict__ item_factors,
    const float* __restrict__ user_biases,
    const float* __restrict__ item_biases,
    const int*   __restrict__ minr_p,
    const int*   __restrict__ maxr_p,
    int L, int F, int B,
    float* __restrict__ out)
{
    const int wavesPerBlock = blockDim.x >> 6;
    const int wave = blockIdx.x * wavesPerBlock + (threadIdx.x >> 6);
    const int lane = threadIdx.x & 63;
    if (wave >= B) return;

    const int u   = users[wave];
    const int it  = items[wave];
    const int pos = item_pos[wave];

    const int   minr = *minr_p;
    const int   maxr = *maxr_p;
    const int   bins = maxr;
    const float fmin = (float)minr;
    const float fmax = (float)maxr;
    const float width = (float)(maxr - minr) / (float)bins;
    const float lo = (float)((minr - 1) > 0 ? (minr - 1) : 0);
    const float hi = (float)(maxr - 1);

    // ---- dot product over F (F==64 expected: 1 element/lane) ----
    float d = 0.f;
    for (int f = lane; f < F; f += 64)
        d += user_factors[(size_t)u * F + f] * item_factors[(size_t)it * F + f];
    #pragma unroll
    for (int o = 32; o > 0; o >>= 1) d += __shfl_xor(d, o, 64);

    const float pred = user_biases[u] + item_biases[it] + d;
    const float end  = fminf(fmaxf(rintf(pred), lo), hi);

    // ---- histogram mass over the ratings row ----
    const float* row = ratings + (size_t)u * L;
    float mass = 0.f;

    // chunks of 256 floats: each lane does one float4 per chunk (L=256 -> 1 iter)
    for (int base = 0; base < (L & ~255); base += 256) {
        float4 r4 = reinterpret_cast<const float4*>(row + base)[lane];
        float rv[4] = {r4.x, r4.y, r4.z, r4.w};
        #pragma unroll
        for (int k = 0; k < 4; ++k) {
            int j = base + lane * 4 + k;
            float r = (j == pos) ? pred : rv[k];
            bool in_range = (r >= fmin) && (r <= fmax);
            float fidx = floorf((r - fmin) / width);
            if (r == fmax) fidx = (float)(bins - 1);
            if (in_range) {
                if (fidx <= end) mass += 1.0f;
                if (fidx == end) mass -= 0.5f;
            }
        }
    }
    // scalar tail for L not multiple of 256
    for (int j = (L & ~255) + lane; j < L; j += 64) {
        float r = (j == pos) ? pred : row[j];
        bool in_range = (r >= fmin) && (r <= fmax);
        float fidx = floorf((r - fmin) / width);
        if (r == fmax) fidx = (float)(bins - 1);
        if (in_range) {
            if (fidx <= end) mass += 1.0f;
            if (fidx == end) mass -= 0.5f;
        }
    }

    #pragma unroll
    for (int o = 32; o > 0; o >>= 1) mass += __shfl_xor(mass, o, 64);

    if (lane == 0) {
        out[2 * wave + 0] = pred;
        out[2 * wave + 1] = mass;
    }
}

extern "C" void kernel_launch(void* const* d_in, const int* in_sizes, int n_in,
                              void* d_out, int out_size, void* d_ws, size_t ws_size,
                              hipStream_t stream) {
    const int*   users        = (const int*)  d_in[0];
    const int*   items        = (const int*)  d_in[1];
    const int*   item_pos     = (const int*)  d_in[2];
    const float* ratings      = (const float*)d_in[3];
    const float* user_factors = (const float*)d_in[4];
    const float* item_factors = (const float*)d_in[5];
    const float* user_biases  = (const float*)d_in[6];
    const float* item_biases  = (const float*)d_in[7];
    const int*   minr_p       = (const int*)  d_in[8];
    const int*   maxr_p       = (const int*)  d_in[9];

    const int B       = in_sizes[0];
    const int N_USERS = in_sizes[6];           // user_biases is (N_USERS, 1)
    const int L       = in_sizes[3] / N_USERS; // ratings is (N_USERS, L)
    const int F       = in_sizes[4] / N_USERS; // user_factors is (N_USERS, F)

    float* out = (float*)d_out;

    const int block = 256;                 // 4 waves per block
    const int wavesPerBlock = block / 64;
    const int grid = (B + wavesPerBlock - 1) / wavesPerBlock;

    hist_mf_kernel<<<grid, block, 0, stream>>>(
        users, items, item_pos, ratings, user_factors, item_factors,
        user_biases, item_biases, minr_p, maxr_p, L, F, B, out);
}